// Round 8
// baseline (4772.525 us; speedup 1.0000x reference)
//
#include <hip/hip_runtime.h>

// ContinuousLSTMLayer B=256,S=512,F=64,H=128; 8192 sequential RK4 stages.
// v12 = ASYMMETRIC WAVE SPECIALIZATION (producer/consumer roles).
// v5-v11 PMC law: MfmaUtil(~52%) + VALUBusy(~52%) ~= 100% of the stage --
// the two pipes run strictly SEQUENTIALLY because the 2 waves/SIMD are
// barrier-locked and SYMMETRIC: both do [share 33 MFMA accepts ~545cy] then
// both do [VALU chains ~560cy]. No same-program reordering fixes this
// (v5-v11). Fix: different PROGRAMS per wave. 4 A-waves compute i/f/g
// preacts (24 MFMA, ~15 VALU, 6 f32 ds_writes); 4 B-waves compute the
// 4-deep o-chain (8 MFMA) + ALL nonlinearity/RK/h-update for 32 cols.
// One A + one B per SIMD (role=(wv^(wv>>2))&1 is bichromatic for both
// plausible wave->SIMD maps) -> B's ~400cy VALU/trans chain co-issues under
// A's ~530cy MFMA accept drain (m114: cross-wave MFMA||VALU overlap).
// c-path deferral unchanged (preacts of stage s consumed at s+1, now via
// double-buffered lds_p instead of register carries; bootstrap: zeroed
// p[0] x d6p=0 -- numerically identical to v7). All zf C-operands gone
// (chains start from bias-carrying x-projection); no PIN_V.

#define B_N 256
#define S_N 512
#define F_N 64
#define H_N 128

typedef _Float16 v8h __attribute__((ext_vector_type(8)));
typedef float v4f __attribute__((ext_vector_type(4)));

#define MFMA16(a, b, c) __builtin_amdgcn_mfma_f32_16x16x32_f16((a), (b), (c), 0, 0, 0)
#define SB0() __builtin_amdgcn_sched_barrier(0)
// lgkm-only barrier (v7-proven): no vmcnt drain; memory ordering via clobber.
#define BAR() do { SB0(); \
                   asm volatile("s_waitcnt lgkmcnt(0)" ::: "memory"); \
                   __builtin_amdgcn_s_barrier(); SB0(); } while (0)

// sigmoid via exp2 + rcp (overflow-safe: rcp(inf)=0)
static __device__ __forceinline__ float sigm(float x) {
  float e = __builtin_amdgcn_exp2f(-1.442695040888963f * x);
  return __builtin_amdgcn_rcpf(1.0f + e);
}

// S1 (deferred c-path of prev stage, role pr) + tail (current-stage h-path)
// for one 16-col tile. All state is suffix-named (no runtime indexing).
#define UPD(SUF) do { \
  float ai = sigm(pi_##SUF); \
  float af = sigm(pf_##SUF); \
  float ag = fmaf(2.0f, sigm(2.0f * pg_##SUF), -1.0f);       /* tanh */ \
  float kc = fmaf(ai, ag, (af - 1.0f) * c_ev_##SUF);         /* i*g+f*c-c */ \
  float cnx; \
  if (pr == 0)      { sum_c_##SUF = kc;                         cnx = fmaf(hdt, kc, c0v_##SUF); } \
  else if (pr == 1) { sum_c_##SUF = fmaf(2.f, kc, sum_c_##SUF); cnx = fmaf(hdt, kc, c0v_##SUF); } \
  else if (pr == 2) { sum_c_##SUF = fmaf(2.f, kc, sum_c_##SUF); cnx = fmaf(dt, kc, c0v_##SUF); } \
  else { \
    float sc = sum_c_##SUF + kc; \
    float dd = cross ? d6p : d6;                              /* ts crossing */ \
    c0v_##SUF = fmaf(dd, sc, c0v_##SUF); \
    cnx = c0v_##SUF; \
  } \
  c_ev_##SUF = cnx; \
  float tc = fmaf(2.0f, sigm(2.0f * c_ev_##SUF), -1.0f);     /* tanh(c) */ \
  float ao = sigm(co_##SUF[0]); \
  float kh = fmaf(ao, tc, -h_ev_##SUF);                      /* o*tanh(c)-h */ \
  if (st == 0)      { sum_h_##SUF = kh;                         hnx_##SUF = fmaf(hdt, kh, h0v_##SUF); } \
  else if (st == 1) { sum_h_##SUF = fmaf(2.f, kh, sum_h_##SUF); hnx_##SUF = fmaf(hdt, kh, h0v_##SUF); } \
  else if (st == 2) { sum_h_##SUF = fmaf(2.f, kh, sum_h_##SUF); hnx_##SUF = fmaf(dt, kh, h0v_##SUF); } \
  else { \
    float sh = sum_h_##SUF + kh; \
    h0v_##SUF = fmaf(d6, sh, h0v_##SUF); \
    hnx_##SUF = h0v_##SUF; \
  } \
  h_ev_##SUF = hnx_##SUF; \
} while (0)

__global__ void __launch_bounds__(512, 2) clstm_mfma12(
    const float* __restrict__ x,    // [B,S,F] f32
    const float* __restrict__ td,   // [B,S]   f32
    const float* __restrict__ Wi, const float* __restrict__ bi,
    const float* __restrict__ Wf, const float* __restrict__ bff,
    const float* __restrict__ Wo, const float* __restrict__ bo,
    const float* __restrict__ Wg, const float* __restrict__ bg,
    float* __restrict__ out)        // [B,S,H] f32
{
  const int b    = blockIdx.x;
  const int t    = threadIdx.x;
  const int wv   = t >> 6;
  const int l    = t & 63;
  const int quad = l >> 4;
  const int role = (wv ^ (wv >> 2)) & 1;                 // 0=A(ifg) 1=B(o+upd)
  const int sl   = ((wv >> 1) & 1) + 2 * ((wv >> 2) & 1); // slice 0..3
  const int n0   = sl * 32 + (l & 15);                   // tile0 col; tile1=+16

  __shared__ alignas(16) _Float16 lds_h[2][H_N];  // double-buffered h (f16)
  __shared__ alignas(16) _Float16 lds_x[F_N];     // current x_t (f16)
  __shared__ float lds_p[2][3][H_N];              // double-buffered preacts i,f,g
  __shared__ float lds_td[S_N];

  // ---- role-specific resident weight fragments (AGPR-friendly, no pins) ----
  v8h BhA[3][2][4]; v8h BxA[3][2][2]; float biA[3][2];   // A: i,f,g
  v8h BhO[2][4];    v8h BxO[2][2];    float biO[2];      // B: o

  if (role == 0) {
    const float* Wg3[3] = {Wi, Wf, Wg};
    const float* bg3[3] = {bi, bff, bg};
#pragma unroll
    for (int g = 0; g < 3; ++g) {
#pragma unroll
      for (int T = 0; T < 2; ++T) {
        const float* W = Wg3[g];
        const int nc = n0 + T * 16;
#pragma unroll
        for (int kt = 0; kt < 4; ++kt) {
          v8h f;
#pragma unroll
          for (int j = 0; j < 8; ++j)
            f[j] = (_Float16)W[(64 + kt * 32 + quad * 8 + j) * H_N + nc];
          BhA[g][T][kt] = f;
        }
#pragma unroll
        for (int kx = 0; kx < 2; ++kx) {
          v8h f;
#pragma unroll
          for (int j = 0; j < 8; ++j)
            f[j] = (_Float16)W[(kx * 32 + quad * 8 + j) * H_N + nc];
          BxA[g][T][kx] = f;
        }
        biA[g][T] = bg3[g][nc];
      }
    }
  } else {
#pragma unroll
    for (int T = 0; T < 2; ++T) {
      const int nc = n0 + T * 16;
#pragma unroll
      for (int kt = 0; kt < 4; ++kt) {
        v8h f;
#pragma unroll
        for (int j = 0; j < 8; ++j)
          f[j] = (_Float16)Wo[(64 + kt * 32 + quad * 8 + j) * H_N + nc];
        BhO[T][kt] = f;
      }
#pragma unroll
      for (int kx = 0; kx < 2; ++kx) {
        v8h f;
#pragma unroll
        for (int j = 0; j < 8; ++j)
          f[j] = (_Float16)Wo[(kx * 32 + quad * 8 + j) * H_N + nc];
        BxO[T][kx] = f;
      }
      biO[T] = bo[nc];
    }
  }

  // ---- LDS setup ----
  lds_td[t] = td[b * S_N + t];
  ((float*)lds_p)[t] = 0.f;                       // zero p (768 floats total)
  if (t < 256) ((float*)lds_p)[512 + t] = 0.f;
  if (t < 32) {
    const float* xr = x + (size_t)b * S_N * F_N;
    lds_x[2 * t]     = (_Float16)xr[2 * t];
    lds_x[2 * t + 1] = (_Float16)xr[2 * t + 1];
  }
  if (t < H_N) lds_h[0][t] = (_Float16)0.0f;
  // first BAR() covers setup visibility (lgkmcnt(0) + s_barrier)

  // ---- per-role state ----
  const v4f zf = {0.f, 0.f, 0.f, 0.f};
  // B-role RK state (per 16-col tile)
  float h0v_0 = 0.f, c0v_0 = 0.f, h_ev_0 = 0.f, c_ev_0 = 0.f, sum_h_0 = 0.f, sum_c_0 = 0.f;
  float h0v_1 = 0.f, c0v_1 = 0.f, h_ev_1 = 0.f, c_ev_1 = 0.f, sum_h_1 = 0.f, sum_c_1 = 0.f;
  float dt = 0.f, hdt = 0.f, d6 = 0.f, d6p = 0.f;
  // x-projections (A: 6, B: 2), refreshed once per timestep
  v4f xpI_0 = zf, xpI_1 = zf, xpF_0 = zf, xpF_1 = zf, xpG_0 = zf, xpG_1 = zf;
  v4f xpO_0 = zf, xpO_1 = zf;
  float xn0 = 0.f, xn1 = 0.f;

  for (int s = 0; s < S_N; ++s) {
#pragma unroll
    for (int ode = 0; ode < 4; ++ode) {
#pragma unroll
      for (int st = 0; st < 4; ++st) {
        BAR();                                 // h(stage), p(prev) now visible
        // ---- common: current A-frags (h) ----
        const _Float16* hb = lds_h[st & 1];
        v8h ah0 = *(const v8h*)(hb + quad * 8);
        v8h ah1 = *(const v8h*)(hb + 32 + quad * 8);
        v8h ah2 = *(const v8h*)(hb + 64 + quad * 8);
        v8h ah3 = *(const v8h*)(hb + 96 + quad * 8);

        if (role == 0) {
          // ================= A-wave: i/f/g preact producer =================
          if (ode == 0 && st == 0) {
            v8h ax0 = *(const v8h*)(lds_x + quad * 8);
            v8h ax1 = *(const v8h*)(lds_x + 32 + quad * 8);
            {
              v4f cb = {biA[0][0], biA[0][0], biA[0][0], biA[0][0]};
              v4f u = MFMA16(ax0, BxA[0][0][0], cb);
              xpI_0 = MFMA16(ax1, BxA[0][0][1], u);
            }
            {
              v4f cb = {biA[0][1], biA[0][1], biA[0][1], biA[0][1]};
              v4f u = MFMA16(ax0, BxA[0][1][0], cb);
              xpI_1 = MFMA16(ax1, BxA[0][1][1], u);
            }
            {
              v4f cb = {biA[1][0], biA[1][0], biA[1][0], biA[1][0]};
              v4f u = MFMA16(ax0, BxA[1][0][0], cb);
              xpF_0 = MFMA16(ax1, BxA[1][0][1], u);
            }
            {
              v4f cb = {biA[1][1], biA[1][1], biA[1][1], biA[1][1]};
              v4f u = MFMA16(ax0, BxA[1][1][0], cb);
              xpF_1 = MFMA16(ax1, BxA[1][1][1], u);
            }
            {
              v4f cb = {biA[2][0], biA[2][0], biA[2][0], biA[2][0]};
              v4f u = MFMA16(ax0, BxA[2][0][0], cb);
              xpG_0 = MFMA16(ax1, BxA[2][0][1], u);
            }
            {
              v4f cb = {biA[2][1], biA[2][1], biA[2][1], biA[2][1]};
              v4f u = MFMA16(ax0, BxA[2][1][0], cb);
              xpG_1 = MFMA16(ax1, BxA[2][1][1], u);
            }
            xn0 = 0.f; xn1 = 0.f;
            if (t < 32 && s + 1 < S_N) {       // t<32 is wave 0 = role A
              const float* xr = x + (size_t)(b * S_N + s + 1) * F_N;
              xn0 = xr[2 * t]; xn1 = xr[2 * t + 1];
            }
          }

          // 6 independent 4-deep chains (i,f,g x 2 tiles), level-interleaved
          v4f aI0 = MFMA16(ah0, BhA[0][0][0], xpI_0);
          v4f aF0 = MFMA16(ah0, BhA[1][0][0], xpF_0);
          v4f aG0 = MFMA16(ah0, BhA[2][0][0], xpG_0);
          v4f aI1 = MFMA16(ah0, BhA[0][1][0], xpI_1);
          v4f aF1 = MFMA16(ah0, BhA[1][1][0], xpF_1);
          v4f aG1 = MFMA16(ah0, BhA[2][1][0], xpG_1);
          aI0 = MFMA16(ah1, BhA[0][0][1], aI0);
          aF0 = MFMA16(ah1, BhA[1][0][1], aF0);
          aG0 = MFMA16(ah1, BhA[2][0][1], aG0);
          aI1 = MFMA16(ah1, BhA[0][1][1], aI1);
          aF1 = MFMA16(ah1, BhA[1][1][1], aF1);
          aG1 = MFMA16(ah1, BhA[2][1][1], aG1);
          aI0 = MFMA16(ah2, BhA[0][0][2], aI0);
          aF0 = MFMA16(ah2, BhA[1][0][2], aF0);
          aG0 = MFMA16(ah2, BhA[2][0][2], aG0);
          aI1 = MFMA16(ah2, BhA[0][1][2], aI1);
          aF1 = MFMA16(ah2, BhA[1][1][2], aF1);
          aG1 = MFMA16(ah2, BhA[2][1][2], aG1);
          aI0 = MFMA16(ah3, BhA[0][0][3], aI0);
          aF0 = MFMA16(ah3, BhA[1][0][3], aF0);
          aG0 = MFMA16(ah3, BhA[2][0][3], aG0);
          aI1 = MFMA16(ah3, BhA[0][1][3], aI1);
          aF1 = MFMA16(ah3, BhA[1][1][3], aF1);
          aG1 = MFMA16(ah3, BhA[2][1][3], aG1);

          // quad q<3 writes gate q's preacts for both tiles (broadcast rows:
          // every lane's [0] is valid for its column)
          float v0 = (quad == 0) ? aI0[0] : (quad == 1) ? aF0[0] : aG0[0];
          float v1 = (quad == 0) ? aI1[0] : (quad == 1) ? aF1[0] : aG1[0];
          if (quad < 3) {
            float* pb = &lds_p[(st & 1) ^ 1][quad][0];
            pb[n0]      = v0;
            pb[n0 + 16] = v1;
          }

          if (ode == 3 && st == 3 && t < 32 && s + 1 < S_N) {
            lds_x[2 * t]     = (_Float16)xn0;  // reg-dep vmcnt wait here
            lds_x[2 * t + 1] = (_Float16)xn1;
          }
        } else {
          // ================= B-wave: o-chain + full update =================
          if (ode == 0 && st == 0) {
            dt  = fminf(lds_td[s], 1.0f) * 0.25f;  // MAX_DT / ODE_STEPS
            hdt = 0.5f * dt;
            d6  = dt * (1.0f / 6.0f);
            v8h ax0 = *(const v8h*)(lds_x + quad * 8);
            v8h ax1 = *(const v8h*)(lds_x + 32 + quad * 8);
            {
              v4f cb = {biO[0], biO[0], biO[0], biO[0]};
              v4f u = MFMA16(ax0, BxO[0][0], cb);
              xpO_0 = MFMA16(ax1, BxO[0][1], u);
            }
            {
              v4f cb = {biO[1], biO[1], biO[1], biO[1]};
              v4f u = MFMA16(ax0, BxO[1][0], cb);
              xpO_1 = MFMA16(ax1, BxO[1][1], u);
            }
          }

          // preacts of the PREVIOUS stage (A wrote them pre-barrier)
          const float* pb = &lds_p[st & 1][0][0];
          float pi_0 = pb[n0],             pi_1 = pb[n0 + 16];
          float pf_0 = pb[H_N + n0],       pf_1 = pb[H_N + n0 + 16];
          float pg_0 = pb[2 * H_N + n0],   pg_1 = pb[2 * H_N + n0 + 16];

          // o: two 4-deep chains, level-interleaved (result ~160cy after issue;
          // covered by the S1 VALU below)
          v4f co_0 = MFMA16(ah0, BhO[0][0], xpO_0);
          v4f co_1 = MFMA16(ah0, BhO[1][0], xpO_1);
          co_0 = MFMA16(ah1, BhO[0][1], co_0);
          co_1 = MFMA16(ah1, BhO[1][1], co_1);
          co_0 = MFMA16(ah2, BhO[0][2], co_0);
          co_1 = MFMA16(ah2, BhO[1][2], co_1);
          co_0 = MFMA16(ah3, BhO[0][3], co_0);
          co_1 = MFMA16(ah3, BhO[1][3], co_1);

          const int pr = (st == 0) ? 3 : st - 1;     // prev stage's RK role
          const bool cross = (ode == 0 && st == 0);  // timestep crossing
          float hnx_0, hnx_1;
          UPD(0);
          UPD(1);

          if (quad == 0) {
            lds_h[(st & 1) ^ 1][n0]      = (_Float16)hnx_0;
            lds_h[(st & 1) ^ 1][n0 + 16] = (_Float16)hnx_1;
          }

          if (ode == 3 && st == 3) {
            if (quad == 0) {
              out[(size_t)(b * S_N + s) * H_N + n0]      = h0v_0;
              out[(size_t)(b * S_N + s) * H_N + n0 + 16] = h0v_1;
            }
            d6p = d6;
          }
        }
      }
    }
  }
}

extern "C" void kernel_launch(void* const* d_in, const int* in_sizes, int n_in,
                              void* d_out, int out_size, void* d_ws, size_t ws_size,
                              hipStream_t stream) {
  (void)in_sizes; (void)n_in; (void)d_ws; (void)ws_size; (void)out_size;
  clstm_mfma12<<<B_N, 512, 0, stream>>>(
      (const float*)d_in[0],  // x
      (const float*)d_in[1],  // time_diffs
      (const float*)d_in[2], (const float*)d_in[3],   // W_i, b_i
      (const float*)d_in[4], (const float*)d_in[5],   // W_f, b_f
      (const float*)d_in[6], (const float*)d_in[7],   // W_o, b_o
      (const float*)d_in[8], (const float*)d_in[9],   // W_g, b_g
      (float*)d_out);
}